// Round 1
// baseline (1358.080 us; speedup 1.0000x reference)
//
#include <hip/hip_runtime.h>
#include <stdint.h>

#define LSTEPS 64
#define BATCH 128
#define HID 256
#define NGATES 1024
#define NVOCAB 32000
#define GO_TOK 31999

typedef __bf16 bf16x8 __attribute__((ext_vector_type(8)));
typedef float f32x4 __attribute__((ext_vector_type(4)));
typedef unsigned short u16;
typedef u16 u16x8 __attribute__((ext_vector_type(8)));

__device__ __forceinline__ u16 f2bf(float f) {
  union { float f; uint32_t u; } v; v.f = f;
  uint32_t u = v.u;
  return (u16)((u + 0x7FFFu + ((u >> 16) & 1u)) >> 16);
}
__device__ __forceinline__ float bf2f(u16 b) {
  union { uint32_t u; float f; } v; v.u = ((uint32_t)b) << 16;
  return v.f;
}
__device__ __forceinline__ float sigm(float x) {
  return 1.0f / (1.0f + __expf(-x));
}
__device__ __forceinline__ float tanh_f(float x) {
  return 2.0f / (1.0f + __expf(-2.0f * x)) - 1.0f;
}

// Pack W [J][256] f32 row-major -> bf16 k-chunked [32][J][8]: dst[kb][j][e] = W[j][kb*8+e]
__global__ void k_pack(const float* __restrict__ src, u16* __restrict__ dst, int J) {
  int j = blockIdx.x * 256 + threadIdx.x;
  int kb = blockIdx.y;
  const float* s = src + (size_t)j * HID + kb * 8;
  u16x8 o;
#pragma unroll
  for (int e = 0; e < 8; ++e) o[e] = f2bf(s[e]);
  *reinterpret_cast<u16x8*>(dst + ((size_t)kb * J + j) * 8) = o;
}

__global__ void k_bsum(const float* __restrict__ a, const float* __restrict__ b, float* __restrict__ o) {
  int i = blockIdx.x * 256 + threadIdx.x;
  o[i] = a[i] + b[i];
}

// Gather embeddings -> X bf16 [8192][256]; row r = t*128+b: t==0 -> GO token
__global__ void k_gather(const int* __restrict__ outs, const float* __restrict__ embW, u16* __restrict__ X) {
  int idx = blockIdx.x * 256 + threadIdx.x;  // chunk of 8 elems; 262144 chunks
  int r = idx >> 5, k8 = idx & 31;
  int t = r >> 7;
  int src = (t == 0) ? GO_TOK : outs[r];
  const float* p = embW + (size_t)src * HID + k8 * 8;
  u16x8 o;
#pragma unroll
  for (int e = 0; e < 8; ++e) o[e] = f2bf(p[e]);
  *reinterpret_cast<u16x8*>(X + (size_t)r * HID + k8 * 8) = o;
}

// C[M][N] = A[M][256](bf16) @ Bp([32][N][8] bf16, i.e. B^T k-chunked) + bias[N]
// grid: (N/64, M/64), block 256. Full K=256 staged in LDS once.
__global__ __launch_bounds__(256, 2) void k_gemm(const u16* __restrict__ A, const u16* __restrict__ Bp,
                                                 const float* __restrict__ bias, float* __restrict__ C,
                                                 int N) {
  __shared__ __align__(16) u16 sA[64 * 256];      // 32 KB, 16B chunks XOR-swizzled by row
  __shared__ __align__(16) u16 sB[32 * 64 * 8];   // 32 KB, [kb][j][8], j XOR-swizzled by kb
  const int tid = threadIdx.x;
  const int m0 = blockIdx.y * 64;
  const int n0 = blockIdx.x * 64;
#pragma unroll
  for (int i = 0; i < 8; ++i) {
    int idx = tid + i * 256;
    int r = idx >> 5, k8 = idx & 31;
    *reinterpret_cast<uint4*>(&sA[(r * 32 + (k8 ^ (r & 7))) * 8]) =
        *reinterpret_cast<const uint4*>(&A[(size_t)(m0 + r) * HID + k8 * 8]);
  }
#pragma unroll
  for (int i = 0; i < 8; ++i) {
    int idx = tid + i * 256;
    int kb = idx >> 6, j = idx & 63;
    *reinterpret_cast<uint4*>(&sB[(kb * 64 + (j ^ ((kb & 3) << 2))) * 8]) =
        *reinterpret_cast<const uint4*>(&Bp[((size_t)kb * N + n0 + j) * 8]);
  }
  __syncthreads();
  const int wave = tid >> 6, lane = tid & 63;
  const int wm = wave >> 1, wn = wave & 1;
  const int lr = lane & 15, lk = lane >> 4;
  f32x4 acc[2][2] = {};
#pragma unroll
  for (int kk = 0; kk < 8; ++kk) {
    bf16x8 a[2], b[2];
    int k8 = kk * 4 + lk;
#pragma unroll
    for (int mt = 0; mt < 2; ++mt) {
      int r = wm * 32 + mt * 16 + lr;
      a[mt] = *reinterpret_cast<const bf16x8*>(&sA[(r * 32 + (k8 ^ (r & 7))) * 8]);
    }
#pragma unroll
    for (int nt = 0; nt < 2; ++nt) {
      int j = wn * 32 + nt * 16 + lr;
      b[nt] = *reinterpret_cast<const bf16x8*>(&sB[(k8 * 64 + (j ^ ((k8 & 3) << 2))) * 8]);
    }
#pragma unroll
    for (int mt = 0; mt < 2; ++mt)
#pragma unroll
      for (int nt = 0; nt < 2; ++nt)
        acc[mt][nt] = __builtin_amdgcn_mfma_f32_16x16x32_bf16(a[mt], b[nt], acc[mt][nt], 0, 0, 0);
  }
#pragma unroll
  for (int mt = 0; mt < 2; ++mt) {
#pragma unroll
    for (int nt = 0; nt < 2; ++nt) {
      int col = n0 + wn * 32 + nt * 16 + lr;
      float bs = bias[col];
#pragma unroll
      for (int i = 0; i < 4; ++i) {
        int row = m0 + wm * 32 + mt * 16 + lk * 4 + i;
        C[(size_t)row * N + col] = acc[mt][nt][i] + bs;
      }
    }
  }
}

// LSTM recurrence: 8 blocks x 512 threads; block bg owns batches bg*16..bg*16+15.
// gates[16][1024] = G[t] + h @ W_hh^T via MFMA, then elementwise update. No grid sync.
__global__ __launch_bounds__(512, 2) void k_recur(const float* __restrict__ G, const u16* __restrict__ Wp,
                                                  const float* __restrict__ h0, const float* __restrict__ c0,
                                                  u16* __restrict__ h_all) {
  __shared__ __align__(16) u16 sh[16 * 256];   // h bf16, swizzled chunks (8 KB)
  __shared__ u16 sg[16 * 1024];                // gates bf16 (32 KB)
  const int bg = blockIdx.x;
  const int tid = threadIdx.x;
  const int wave = tid >> 6, lane = tid & 63;
  const int lr = lane & 15, lk = lane >> 4;
  {  // h0 -> sh (512 chunks, one per thread)
    int r = tid >> 5, k8 = tid & 31;
    const float* p = h0 + (size_t)(bg * 16 + r) * HID + k8 * 8;
    u16x8 o;
#pragma unroll
    for (int e = 0; e < 8; ++e) o[e] = f2bf(p[e]);
    *reinterpret_cast<u16x8*>(&sh[(r * 32 + (k8 ^ (r & 7))) * 8]) = o;
  }
  const int b = tid >> 5, dc = tid & 31;
  float c[8];
#pragma unroll
  for (int i = 0; i < 8; ++i) c[i] = c0[(size_t)(bg * 16 + b) * HID + dc + 32 * i];
  __syncthreads();

  for (int t = 0; t < LSTEPS; ++t) {
    const float* gsrc = G + ((size_t)t * BATCH + bg * 16) * NGATES;
    for (int j8 = 0; j8 < 8; ++j8) {
      const int jt = wave * 8 + j8;
      f32x4 acc0 = {}, acc1 = {};
#pragma unroll
      for (int kk = 0; kk < 4; ++kk) {
        int k8a = kk * 8 + lk;      // even group
        int k8b = kk * 8 + 4 + lk;  // odd group
        bf16x8 a0 = *reinterpret_cast<const bf16x8*>(&sh[(lr * 32 + (k8a ^ (lr & 7))) * 8]);
        bf16x8 b0 = *reinterpret_cast<const bf16x8*>(&Wp[((size_t)k8a * NGATES + jt * 16 + lr) * 8]);
        acc0 = __builtin_amdgcn_mfma_f32_16x16x32_bf16(a0, b0, acc0, 0, 0, 0);
        bf16x8 a1 = *reinterpret_cast<const bf16x8*>(&sh[(lr * 32 + (k8b ^ (lr & 7))) * 8]);
        bf16x8 b1 = *reinterpret_cast<const bf16x8*>(&Wp[((size_t)k8b * NGATES + jt * 16 + lr) * 8]);
        acc1 = __builtin_amdgcn_mfma_f32_16x16x32_bf16(a1, b1, acc1, 0, 0, 0);
      }
      f32x4 acc = acc0 + acc1;
      int col = jt * 16 + lr;
#pragma unroll
      for (int i = 0; i < 4; ++i) {
        int row = lk * 4 + i;
        sg[row * NGATES + col] = f2bf(acc[i] + gsrc[(size_t)row * NGATES + col]);
      }
    }
    __syncthreads();
#pragma unroll
    for (int i = 0; i < 8; ++i) {
      int d = dc + 32 * i;
      float ig = bf2f(sg[b * NGATES + d]);
      float fg = bf2f(sg[b * NGATES + 256 + d]);
      float gg = bf2f(sg[b * NGATES + 512 + d]);
      float og = bf2f(sg[b * NGATES + 768 + d]);
      float cn = sigm(fg) * c[i] + sigm(ig) * tanh_f(gg);
      c[i] = cn;
      float hn = sigm(og) * tanh_f(cn);
      u16 hb = f2bf(hn);
      h_all[((size_t)t * BATCH + bg * 16 + b) * HID + d] = hb;
      sh[(b * 32 + ((d >> 3) ^ (b & 7))) * 8 + (d & 7)] = hb;
    }
    __syncthreads();
  }
}

extern "C" void kernel_launch(void* const* d_in, const int* in_sizes, int n_in,
                              void* d_out, int out_size, void* d_ws, size_t ws_size,
                              hipStream_t stream) {
  const int* outs = (const int*)d_in[0];
  const float* h0 = (const float*)d_in[1];
  const float* c0 = (const float*)d_in[2];
  const float* embW = (const float*)d_in[4];
  const float* W_ih = (const float*)d_in[5];
  const float* W_hh = (const float*)d_in[6];
  const float* b_ih = (const float*)d_in[7];
  const float* b_hh = (const float*)d_in[8];
  const float* proj_W = (const float*)d_in[9];
  const float* proj_b = (const float*)d_in[10];
  float* out = (float*)d_out;

  char* ws = (char*)d_ws;
  u16* Xbf     = (u16*)(ws + 0);           //  4,194,304 B  [8192][256] bf16
  u16* WihTp   = (u16*)(ws + 4194304);     //    524,288 B  [32][1024][8]
  u16* WhhTp   = (u16*)(ws + 4718592);     //    524,288 B  [32][1024][8]
  u16* projWTp = (u16*)(ws + 5242880);     // 16,384,000 B  [32][32000][8]
  float* G     = (float*)(ws + 21626880);  // 33,554,432 B  [64][128][1024] f32
  u16* h_all   = (u16*)(ws + 55181312);    //  4,194,304 B  [64][128][256] bf16
  float* bsum  = (float*)(ws + 59375616);  //      4,096 B

  k_pack<<<dim3(4, 32), 256, 0, stream>>>(W_ih, WihTp, NGATES);
  k_pack<<<dim3(4, 32), 256, 0, stream>>>(W_hh, WhhTp, NGATES);
  k_pack<<<dim3(125, 32), 256, 0, stream>>>(proj_W, projWTp, NVOCAB);
  k_bsum<<<dim3(4), 256, 0, stream>>>(b_ih, b_hh, bsum);
  k_gather<<<dim3(1024), 256, 0, stream>>>(outs, embW, Xbf);
  // G = X @ W_ih^T + (b_ih + b_hh): M=8192, N=1024
  k_gemm<<<dim3(16, 128), 256, 0, stream>>>(Xbf, WihTp, bsum, G, NGATES);
  // 64-step LSTM recurrence
  k_recur<<<dim3(8), 512, 0, stream>>>(G, WhhTp, h0, c0, h_all);
  // logits = h_all @ proj_W^T + proj_b: M=8192, N=32000
  k_gemm<<<dim3(500, 128), 256, 0, stream>>>(h_all, projWTp, proj_b, out, NVOCAB);
}

// Round 2
// 698.373 us; speedup vs baseline: 1.9446x; 1.9446x over previous
//
#include <hip/hip_runtime.h>
#include <stdint.h>

#define LSTEPS 64
#define BATCH 128
#define HID 256
#define NGATES 1024
#define NVOCAB 32000
#define GO_TOK 31999

typedef __bf16 bf16x8 __attribute__((ext_vector_type(8)));
typedef float f32x4 __attribute__((ext_vector_type(4)));
typedef unsigned short u16;
typedef u16 u16x8 __attribute__((ext_vector_type(8)));

__device__ __forceinline__ u16 f2bf(float f) {
  union { float f; uint32_t u; } v; v.f = f;
  uint32_t u = v.u;
  return (u16)((u + 0x7FFFu + ((u >> 16) & 1u)) >> 16);
}
__device__ __forceinline__ float sigm(float x) {
  return 1.0f / (1.0f + __expf(-x));
}
__device__ __forceinline__ float tanh_f(float x) {
  return 2.0f / (1.0f + __expf(-2.0f * x)) - 1.0f;
}

// Pack W [J][256] f32 row-major -> bf16 k-chunked [32][J][8]: dst[kb][j][e] = W[j][kb*8+e]
__global__ void k_pack(const float* __restrict__ src, u16* __restrict__ dst, int J) {
  int j = blockIdx.x * 256 + threadIdx.x;
  int kb = blockIdx.y;
  const float* s = src + (size_t)j * HID + kb * 8;
  u16x8 o;
#pragma unroll
  for (int e = 0; e < 8; ++e) o[e] = f2bf(s[e]);
  *reinterpret_cast<u16x8*>(dst + ((size_t)kb * J + j) * 8) = o;
}

__global__ void k_bsum(const float* __restrict__ a, const float* __restrict__ b, float* __restrict__ o) {
  int i = blockIdx.x * 256 + threadIdx.x;
  o[i] = a[i] + b[i];
}

// Gather embeddings -> X bf16 [8192][256]; row r = t*128+b: t==0 -> GO token
__global__ void k_gather(const int* __restrict__ outs, const float* __restrict__ embW, u16* __restrict__ X) {
  int idx = blockIdx.x * 256 + threadIdx.x;
  int r = idx >> 5, k8 = idx & 31;
  int t = r >> 7;
  int src = (t == 0) ? GO_TOK : outs[r];
  const float* p = embW + (size_t)src * HID + k8 * 8;
  u16x8 o;
#pragma unroll
  for (int e = 0; e < 8; ++e) o[e] = f2bf(p[e]);
  *reinterpret_cast<u16x8*>(X + (size_t)r * HID + k8 * 8) = o;
}

// C[M][N] = A[M][256](bf16) @ Bp([32][N][8] bf16) + bias[N]  (projection)
__global__ __launch_bounds__(256, 2) void k_gemm(const u16* __restrict__ A, const u16* __restrict__ Bp,
                                                 const float* __restrict__ bias, float* __restrict__ C,
                                                 int N) {
  __shared__ __align__(16) u16 sA[64 * 256];
  __shared__ __align__(16) u16 sB[32 * 64 * 8];
  const int tid = threadIdx.x;
  const int m0 = blockIdx.y * 64;
  const int n0 = blockIdx.x * 64;
#pragma unroll
  for (int i = 0; i < 8; ++i) {
    int idx = tid + i * 256;
    int r = idx >> 5, k8 = idx & 31;
    *reinterpret_cast<uint4*>(&sA[(r * 32 + (k8 ^ (r & 7))) * 8]) =
        *reinterpret_cast<const uint4*>(&A[(size_t)(m0 + r) * HID + k8 * 8]);
  }
#pragma unroll
  for (int i = 0; i < 8; ++i) {
    int idx = tid + i * 256;
    int kb = idx >> 6, j = idx & 63;
    *reinterpret_cast<uint4*>(&sB[(kb * 64 + (j ^ ((kb & 3) << 2))) * 8]) =
        *reinterpret_cast<const uint4*>(&Bp[((size_t)kb * N + n0 + j) * 8]);
  }
  __syncthreads();
  const int wave = tid >> 6, lane = tid & 63;
  const int wm = wave >> 1, wn = wave & 1;
  const int lr = lane & 15, lk = lane >> 4;
  f32x4 acc[2][2] = {};
#pragma unroll
  for (int kk = 0; kk < 8; ++kk) {
    bf16x8 a[2], b[2];
    int k8 = kk * 4 + lk;
#pragma unroll
    for (int mt = 0; mt < 2; ++mt) {
      int r = wm * 32 + mt * 16 + lr;
      a[mt] = *reinterpret_cast<const bf16x8*>(&sA[(r * 32 + (k8 ^ (r & 7))) * 8]);
    }
#pragma unroll
    for (int nt = 0; nt < 2; ++nt) {
      int j = wn * 32 + nt * 16 + lr;
      b[nt] = *reinterpret_cast<const bf16x8*>(&sB[(k8 * 64 + (j ^ ((k8 & 3) << 2))) * 8]);
    }
#pragma unroll
    for (int mt = 0; mt < 2; ++mt)
#pragma unroll
      for (int nt = 0; nt < 2; ++nt)
        acc[mt][nt] = __builtin_amdgcn_mfma_f32_16x16x32_bf16(a[mt], b[nt], acc[mt][nt], 0, 0, 0);
  }
#pragma unroll
  for (int mt = 0; mt < 2; ++mt) {
#pragma unroll
    for (int nt = 0; nt < 2; ++nt) {
      int col = n0 + wn * 32 + nt * 16 + lr;
      float bs = bias[col];
#pragma unroll
      for (int i = 0; i < 4; ++i) {
        int row = m0 + wm * 32 + mt * 16 + lk * 4 + i;
        C[(size_t)row * N + col] = acc[mt][nt][i] + bs;
      }
    }
  }
}

// Fused LSTM recurrence: 32 wgs = 8 batch-groups (bg) x 4 d-slices (q).
// W_ih/W_hh slices live in REGISTERS (64 VGPR each). gates = x@Wih^T + h@Whh^T + b.
// Per-step cross-wg h exchange through h_all (agent-scope atomics) + flag spin barrier.
__global__ __launch_bounds__(512) void k_recur2(const u16* __restrict__ Xbf,
                                                const u16* __restrict__ WihTp,
                                                const u16* __restrict__ WhhTp,
                                                const float* __restrict__ bsum,
                                                const float* __restrict__ h0,
                                                const float* __restrict__ c0,
                                                u16* __restrict__ h_all,
                                                unsigned* __restrict__ flags) {
  __shared__ __align__(16) u16 sh[16 * 256];     // h tile, k8-swizzled per row
  __shared__ __align__(16) u16 sx[2][16 * 256];  // x tiles (double buffer)
  __shared__ float sg[16][260];                  // gates f32, padded
  const int bg = blockIdx.x & 7;
  const int q = blockIdx.x >> 3;
  const int tid = threadIdx.x;
  const int w = tid >> 6, lane = tid & 63;
  const int lr = lane & 15, lk = lane >> 4;

  // --- weight fragments into registers ---
  bf16x8 whh[2][8], wih[2][8];
  float biasv[2];
#pragma unroll
  for (int nt = 0; nt < 2; ++nt) {
    int j = w * 32 + nt * 16 + lr;        // local gate col 0..255
    int g = j >> 6, dloc = j & 63;
    int jg = g * 256 + q * 64 + dloc;     // global gate col
    biasv[nt] = bsum[jg];
#pragma unroll
    for (int kk = 0; kk < 8; ++kk) {
      int k8 = kk * 4 + lk;
      whh[nt][kk] = *reinterpret_cast<const bf16x8*>(&WhhTp[((size_t)k8 * NGATES + jg) * 8]);
      wih[nt][kk] = *reinterpret_cast<const bf16x8*>(&WihTp[((size_t)k8 * NGATES + jg) * 8]);
    }
  }
  // --- c state in registers (nonlinearity mapping: b = tid>>5, dims 2*dl, 2*dl+1) ---
  const int b = tid >> 5, dl = tid & 31;
  float2 c2 = *reinterpret_cast<const float2*>(&c0[(size_t)(bg * 16 + b) * HID + q * 64 + 2 * dl]);
  // --- stage h0 (f32->bf16) and X[0] ---
  {
    int r = tid >> 5, k8 = tid & 31;
    const float* p = h0 + (size_t)(bg * 16 + r) * HID + k8 * 8;
    u16x8 o;
#pragma unroll
    for (int e = 0; e < 8; ++e) o[e] = f2bf(p[e]);
    *reinterpret_cast<u16x8*>(&sh[(r * 32 + (k8 ^ (r & 7))) * 8]) = o;
    *reinterpret_cast<uint4*>(&sx[0][(r * 32 + (k8 ^ (r & 7))) * 8]) =
        *reinterpret_cast<const uint4*>(&Xbf[(size_t)(bg * 16 + r) * HID + k8 * 8]);
  }
  uint4 xpref = *reinterpret_cast<const uint4*>(
      &Xbf[(size_t)(BATCH + bg * 16 + (tid >> 5)) * HID + (tid & 31) * 8]);
  __syncthreads();

  for (int t = 0; t < LSTEPS; ++t) {
    // gates MFMA: 2 N-tiles x (8 h-frags + 8 x-frags)
    f32x4 acch[2] = {}, accx[2] = {};
    const u16* sxc = sx[t & 1];
#pragma unroll
    for (int kk = 0; kk < 8; ++kk) {
      int k8 = kk * 4 + lk;
      int off = (lr * 32 + (k8 ^ (lr & 7))) * 8;
      bf16x8 ah = *reinterpret_cast<const bf16x8*>(&sh[off]);
      bf16x8 ax = *reinterpret_cast<const bf16x8*>(&sxc[off]);
      acch[0] = __builtin_amdgcn_mfma_f32_16x16x32_bf16(ah, whh[0][kk], acch[0], 0, 0, 0);
      acch[1] = __builtin_amdgcn_mfma_f32_16x16x32_bf16(ah, whh[1][kk], acch[1], 0, 0, 0);
      accx[0] = __builtin_amdgcn_mfma_f32_16x16x32_bf16(ax, wih[0][kk], accx[0], 0, 0, 0);
      accx[1] = __builtin_amdgcn_mfma_f32_16x16x32_bf16(ax, wih[1][kk], accx[1], 0, 0, 0);
    }
#pragma unroll
    for (int nt = 0; nt < 2; ++nt) {
      f32x4 s = acch[nt] + accx[nt];
      int col = w * 32 + nt * 16 + lr;
#pragma unroll
      for (int i = 0; i < 4; ++i) sg[lk * 4 + i][col] = s[i] + biasv[nt];
    }
    __syncthreads();
    // nonlinearity for dims (2dl, 2dl+1) of batch b
    {
      float ig0 = sg[b][2 * dl], ig1 = sg[b][2 * dl + 1];
      float fg0 = sg[b][64 + 2 * dl], fg1 = sg[b][64 + 2 * dl + 1];
      float gg0 = sg[b][128 + 2 * dl], gg1 = sg[b][128 + 2 * dl + 1];
      float og0 = sg[b][192 + 2 * dl], og1 = sg[b][192 + 2 * dl + 1];
      float cn0 = sigm(fg0) * c2.x + sigm(ig0) * tanh_f(gg0);
      float cn1 = sigm(fg1) * c2.y + sigm(ig1) * tanh_f(gg1);
      c2.x = cn0; c2.y = cn1;
      float hx = sigm(og0) * tanh_f(cn0);
      float hy = sigm(og1) * tanh_f(cn1);
      unsigned hp = (unsigned)f2bf(hx) | ((unsigned)f2bf(hy) << 16);
      unsigned* dst = (unsigned*)(h_all + ((size_t)t * BATCH + bg * 16 + b) * HID + q * 64 + 2 * dl);
      __hip_atomic_store(dst, hp, __ATOMIC_RELAXED, __HIP_MEMORY_SCOPE_AGENT);
    }
    // stage X[t+1] into the other sx buffer; prefetch X[t+2]
    if (t < LSTEPS - 1) {
      int r = tid >> 5, k8 = tid & 31;
      *reinterpret_cast<uint4*>(&sx[(t + 1) & 1][(r * 32 + (k8 ^ (r & 7))) * 8]) = xpref;
      if (t < LSTEPS - 2)
        xpref = *reinterpret_cast<const uint4*>(
            &Xbf[(size_t)((t + 2) * BATCH + bg * 16 + r) * HID + k8 * 8]);
    }
    __syncthreads();  // all h stores issued + sx staged
    if (t < LSTEPS - 1) {
      if (tid == 0)
        __hip_atomic_store(&flags[blockIdx.x * 16], (unsigned)(t + 1), __ATOMIC_RELEASE,
                           __HIP_MEMORY_SCOPE_AGENT);
      if (tid < 3) {
        int pq = (q + 1 + tid) & 3;
        const unsigned* f = &flags[(pq * 8 + bg) * 16];
        int it = 0;
        unsigned v;
        do {
          v = __hip_atomic_load(f, __ATOMIC_ACQUIRE, __HIP_MEMORY_SCOPE_AGENT);
        } while (v <= (unsigned)t && ++it < (1 << 22));
      }
      __syncthreads();
      // reload full h_{t+1} from h_all[t] (agent-coherent loads)
      int r = tid >> 5, k8 = tid & 31;
      const unsigned long long* src =
          (const unsigned long long*)(h_all + ((size_t)t * BATCH + bg * 16 + r) * HID + k8 * 8);
      unsigned long long v0 = __hip_atomic_load(src, __ATOMIC_RELAXED, __HIP_MEMORY_SCOPE_AGENT);
      unsigned long long v1 = __hip_atomic_load(src + 1, __ATOMIC_RELAXED, __HIP_MEMORY_SCOPE_AGENT);
      unsigned long long* d = (unsigned long long*)&sh[(r * 32 + (k8 ^ (r & 7))) * 8];
      d[0] = v0;
      d[1] = v1;
      __syncthreads();
    }
  }
}

extern "C" void kernel_launch(void* const* d_in, const int* in_sizes, int n_in,
                              void* d_out, int out_size, void* d_ws, size_t ws_size,
                              hipStream_t stream) {
  const int* outs = (const int*)d_in[0];
  const float* h0 = (const float*)d_in[1];
  const float* c0 = (const float*)d_in[2];
  const float* embW = (const float*)d_in[4];
  const float* W_ih = (const float*)d_in[5];
  const float* W_hh = (const float*)d_in[6];
  const float* b_ih = (const float*)d_in[7];
  const float* b_hh = (const float*)d_in[8];
  const float* proj_W = (const float*)d_in[9];
  const float* proj_b = (const float*)d_in[10];
  float* out = (float*)d_out;

  char* ws = (char*)d_ws;
  u16* Xbf      = (u16*)(ws + 0);           //  4,194,304 B  [64][128][256] bf16
  u16* WihTp    = (u16*)(ws + 4194304);     //    524,288 B  [32][1024][8]
  u16* WhhTp    = (u16*)(ws + 4718592);     //    524,288 B  [32][1024][8]
  u16* projWTp  = (u16*)(ws + 5242880);     // 16,384,000 B  [32][32000][8]
  u16* h_all    = (u16*)(ws + 21626880);    //  4,194,304 B  [64][128][256] bf16
  float* bsum   = (float*)(ws + 25821184);  //      4,096 B
  unsigned* flags = (unsigned*)(ws + 25825280);  // 2,048 B (32 slots x 64 B)

  hipMemsetAsync(flags, 0, 32 * 16 * sizeof(unsigned), stream);
  k_pack<<<dim3(4, 32), 256, 0, stream>>>(W_ih, WihTp, NGATES);
  k_pack<<<dim3(4, 32), 256, 0, stream>>>(W_hh, WhhTp, NGATES);
  k_pack<<<dim3(125, 32), 256, 0, stream>>>(proj_W, projWTp, NVOCAB);
  k_bsum<<<dim3(4), 256, 0, stream>>>(b_ih, b_hh, bsum);
  k_gather<<<dim3(1024), 256, 0, stream>>>(outs, embW, Xbf);
  // fused X-GEMM + 64-step LSTM recurrence (32 wgs, register-resident weights)
  k_recur2<<<dim3(32), 512, 0, stream>>>(Xbf, WihTp, WhhTp, bsum, h0, c0, h_all, flags);
  // logits = h_all @ proj_W^T + proj_b: M=8192, N=32000
  k_gemm<<<dim3(500, 128), 256, 0, stream>>>(h_all, projWTp, proj_b, out, NVOCAB);
}

// Round 3
// 618.456 us; speedup vs baseline: 2.1959x; 1.1292x over previous
//
#include <hip/hip_runtime.h>
#include <stdint.h>

#define LSTEPS 64
#define BATCH 128
#define HID 256
#define NGATES 1024
#define NVOCAB 32000
#define GO_TOK 31999

typedef __bf16 bf16x8 __attribute__((ext_vector_type(8)));
typedef float f32x4 __attribute__((ext_vector_type(4)));
typedef unsigned short u16;
typedef u16 u16x8 __attribute__((ext_vector_type(8)));

#define GLDS16(gp, lp)                                                          \
  __builtin_amdgcn_global_load_lds(                                             \
      (const __attribute__((address_space(1))) void*)(gp),                      \
      (__attribute__((address_space(3))) void*)(lp), 16, 0, 0)

__device__ __forceinline__ u16 f2bf(float f) {
  union { float f; uint32_t u; } v; v.f = f;
  uint32_t u = v.u;
  return (u16)((u + 0x7FFFu + ((u >> 16) & 1u)) >> 16);
}
__device__ __forceinline__ float sigm(float x) {
  return 1.0f / (1.0f + __expf(-x));
}
__device__ __forceinline__ float tanh_f(float x) {
  return 2.0f / (1.0f + __expf(-2.0f * x)) - 1.0f;
}

// Pack W [J][256] f32 -> bf16 k-chunked [32][J][8] (for register fragments in recur2)
__global__ void k_pack(const float* __restrict__ src, u16* __restrict__ dst, int J) {
  int j = blockIdx.x * 256 + threadIdx.x;
  int kb = blockIdx.y;
  const float* s = src + (size_t)j * HID + kb * 8;
  u16x8 o;
#pragma unroll
  for (int e = 0; e < 8; ++e) o[e] = f2bf(s[e]);
  *reinterpret_cast<u16x8*>(dst + ((size_t)kb * J + j) * 8) = o;
}

// Plain f32 -> bf16 row-major copy (projW for GEMM B-operand)
__global__ void k_pack2(const float* __restrict__ src, u16* __restrict__ dst) {
  int i = blockIdx.x * 256 + threadIdx.x;  // 8-elem chunk
  const float* s = src + (size_t)i * 8;
  u16x8 o;
#pragma unroll
  for (int e = 0; e < 8; ++e) o[e] = f2bf(s[e]);
  *reinterpret_cast<u16x8*>(dst + (size_t)i * 8) = o;
}

__global__ void k_bsum(const float* __restrict__ a, const float* __restrict__ b, float* __restrict__ o) {
  int i = blockIdx.x * 256 + threadIdx.x;
  o[i] = a[i] + b[i];
}

// Gather embeddings -> X bf16 [8192][256]; row r = t*128+b: t==0 -> GO token
__global__ void k_gather(const int* __restrict__ outs, const float* __restrict__ embW, u16* __restrict__ X) {
  int idx = blockIdx.x * 256 + threadIdx.x;
  int r = idx >> 5, k8 = idx & 31;
  int t = r >> 7;
  int src = (t == 0) ? GO_TOK : outs[r];
  const float* p = embW + (size_t)src * HID + k8 * 8;
  u16x8 o;
#pragma unroll
  for (int e = 0; e < 8; ++e) o[e] = f2bf(p[e]);
  *reinterpret_cast<u16x8*>(X + (size_t)r * HID + k8 * 8) = o;
}

// Projection GEMM: C[8192][32000] = A[8192][256](bf16) @ B[32000][256]^T (bf16) + bias
// 128x128 tile, BK=64 double-buffered, global_load_lds(16B) with inverse-swizzled
// source + XOR-swizzled ds_read_b128, XCD-chunked block swizzle.
__global__ __launch_bounds__(256, 2) void k_gemm2(const u16* __restrict__ A,
                                                  const u16* __restrict__ B,
                                                  const float* __restrict__ bias,
                                                  float* __restrict__ C) {
  __shared__ __align__(16) u16 sA[2][128 * 64];
  __shared__ __align__(16) u16 sB[2][128 * 64];
  const int tid = threadIdx.x;
  const int w = tid >> 6, lane = tid & 63;
  const int lr = lane & 15, lk = lane >> 4;
  const int wm = w >> 1, wn = w & 1;
  // bijective XCD-chunk swizzle (16000 % 8 == 0), N-major walk within chunk
  const int bid = blockIdx.x;
  const int swz = (bid & 7) * 2000 + (bid >> 3);
  const int bx = swz >> 6;   // N-block 0..249
  const int by = swz & 63;   // M-block 0..63
  const int m0 = by << 7, n0 = bx << 7;

  // stage one 128x64 bf16 tile: LDS linear [row][8 chunks], source chunk = cc ^ (row&7)
#define STAGE_TILE(sbuf, gbase, row0)                                            \
  {                                                                              \
    _Pragma("unroll") for (int i = 0; i < 4; ++i) {                              \
      int c = (w * 4 + i) * 64 + lane;                                           \
      int row = c >> 3, cc = c & 7;                                              \
      int scc = cc ^ (row & 7);                                                  \
      GLDS16(&(gbase)[(size_t)((row0) + row) * HID + k0 + scc * 8],              \
             &(sbuf)[(w * 4 + i) * 512]);                                        \
    }                                                                            \
  }

  {
    const int k0 = 0;
    STAGE_TILE(sA[0], A, m0)
    STAGE_TILE(sB[0], B, n0)
  }
  __syncthreads();

  f32x4 acc[4][4] = {};
  int buf = 0;
  for (int ks = 0; ks < 4; ++ks) {
    if (ks < 3) {
      const int k0 = (ks + 1) * 64;
      STAGE_TILE(sA[buf ^ 1], A, m0)
      STAGE_TILE(sB[buf ^ 1], B, n0)
    }
    const u16* sAc = sA[buf];
    const u16* sBc = sB[buf];
#pragma unroll
    for (int kk = 0; kk < 2; ++kk) {
      bf16x8 a[4], b[4];
#pragma unroll
      for (int mt = 0; mt < 4; ++mt) {
        int r = wm * 64 + mt * 16 + lr;
        a[mt] = *reinterpret_cast<const bf16x8*>(&sAc[(r * 8 + ((kk * 4 + lk) ^ (r & 7))) * 8]);
      }
#pragma unroll
      for (int nt = 0; nt < 4; ++nt) {
        int r = wn * 64 + nt * 16 + lr;
        b[nt] = *reinterpret_cast<const bf16x8*>(&sBc[(r * 8 + ((kk * 4 + lk) ^ (r & 7))) * 8]);
      }
#pragma unroll
      for (int mt = 0; mt < 4; ++mt)
#pragma unroll
        for (int nt = 0; nt < 4; ++nt)
          acc[mt][nt] = __builtin_amdgcn_mfma_f32_16x16x32_bf16(a[mt], b[nt], acc[mt][nt], 0, 0, 0);
    }
    __syncthreads();
    buf ^= 1;
  }
#undef STAGE_TILE

  float bs[4];
#pragma unroll
  for (int nt = 0; nt < 4; ++nt) bs[nt] = bias[n0 + wn * 64 + nt * 16 + lr];
#pragma unroll
  for (int mt = 0; mt < 4; ++mt) {
#pragma unroll
    for (int i = 0; i < 4; ++i) {
      int row = m0 + wm * 64 + mt * 16 + lk * 4 + i;
      float* cp = &C[(size_t)row * NVOCAB + n0 + wn * 64];
#pragma unroll
      for (int nt = 0; nt < 4; ++nt) cp[nt * 16 + lr] = acc[mt][nt][i] + bs[nt];
    }
  }
}

// Fused LSTM recurrence: 32 wgs = 8 batch-groups (bg) x 4 d-slices (q).
// W_ih/W_hh slices in registers. accx (x-part) for step t+1 computed inside the
// spin window (no partner dependency) to hide the cross-wg exchange latency.
__global__ __launch_bounds__(512) void k_recur2(const u16* __restrict__ Xbf,
                                                const u16* __restrict__ WihTp,
                                                const u16* __restrict__ WhhTp,
                                                const float* __restrict__ bsum,
                                                const float* __restrict__ h0,
                                                const float* __restrict__ c0,
                                                u16* __restrict__ h_all,
                                                unsigned* __restrict__ flags) {
  __shared__ __align__(16) u16 sh[16 * 256];
  __shared__ __align__(16) u16 sx[2][16 * 256];
  __shared__ float sg[16][260];
  const int bg = blockIdx.x & 7;
  const int q = blockIdx.x >> 3;
  const int tid = threadIdx.x;
  const int w = tid >> 6, lane = tid & 63;
  const int lr = lane & 15, lk = lane >> 4;

  bf16x8 whh[2][8], wih[2][8];
  float biasv[2];
#pragma unroll
  for (int nt = 0; nt < 2; ++nt) {
    int j = w * 32 + nt * 16 + lr;
    int g = j >> 6, dloc = j & 63;
    int jg = g * 256 + q * 64 + dloc;
    biasv[nt] = bsum[jg];
#pragma unroll
    for (int kk = 0; kk < 8; ++kk) {
      int k8 = kk * 4 + lk;
      whh[nt][kk] = *reinterpret_cast<const bf16x8*>(&WhhTp[((size_t)k8 * NGATES + jg) * 8]);
      wih[nt][kk] = *reinterpret_cast<const bf16x8*>(&WihTp[((size_t)k8 * NGATES + jg) * 8]);
    }
  }
  const int b = tid >> 5, dl = tid & 31;
  float2 c2 = *reinterpret_cast<const float2*>(&c0[(size_t)(bg * 16 + b) * HID + q * 64 + 2 * dl]);
  {
    int r = tid >> 5, k8 = tid & 31;
    const float* p = h0 + (size_t)(bg * 16 + r) * HID + k8 * 8;
    u16x8 o;
#pragma unroll
    for (int e = 0; e < 8; ++e) o[e] = f2bf(p[e]);
    *reinterpret_cast<u16x8*>(&sh[(r * 32 + (k8 ^ (r & 7))) * 8]) = o;
    *reinterpret_cast<uint4*>(&sx[0][(r * 32 + (k8 ^ (r & 7))) * 8]) =
        *reinterpret_cast<const uint4*>(&Xbf[(size_t)(bg * 16 + r) * HID + k8 * 8]);
  }
  uint4 xpref = *reinterpret_cast<const uint4*>(
      &Xbf[(size_t)(BATCH + bg * 16 + (tid >> 5)) * HID + (tid & 31) * 8]);
  __syncthreads();

  // accx for t=0
  f32x4 accx[2] = {};
#pragma unroll
  for (int kk = 0; kk < 8; ++kk) {
    int k8 = kk * 4 + lk;
    bf16x8 ax = *reinterpret_cast<const bf16x8*>(&sx[0][(lr * 32 + (k8 ^ (lr & 7))) * 8]);
    accx[0] = __builtin_amdgcn_mfma_f32_16x16x32_bf16(ax, wih[0][kk], accx[0], 0, 0, 0);
    accx[1] = __builtin_amdgcn_mfma_f32_16x16x32_bf16(ax, wih[1][kk], accx[1], 0, 0, 0);
  }

  for (int t = 0; t < LSTEPS; ++t) {
    // h-part MFMAs
    f32x4 acch[2] = {};
#pragma unroll
    for (int kk = 0; kk < 8; ++kk) {
      int k8 = kk * 4 + lk;
      bf16x8 ah = *reinterpret_cast<const bf16x8*>(&sh[(lr * 32 + (k8 ^ (lr & 7))) * 8]);
      acch[0] = __builtin_amdgcn_mfma_f32_16x16x32_bf16(ah, whh[0][kk], acch[0], 0, 0, 0);
      acch[1] = __builtin_amdgcn_mfma_f32_16x16x32_bf16(ah, whh[1][kk], acch[1], 0, 0, 0);
    }
#pragma unroll
    for (int nt = 0; nt < 2; ++nt) {
      f32x4 s = acch[nt] + accx[nt];
      int col = w * 32 + nt * 16 + lr;
#pragma unroll
      for (int i = 0; i < 4; ++i) sg[lk * 4 + i][col] = s[i] + biasv[nt];
    }
    __syncthreads();
    {
      float ig0 = sg[b][2 * dl], ig1 = sg[b][2 * dl + 1];
      float fg0 = sg[b][64 + 2 * dl], fg1 = sg[b][64 + 2 * dl + 1];
      float gg0 = sg[b][128 + 2 * dl], gg1 = sg[b][128 + 2 * dl + 1];
      float og0 = sg[b][192 + 2 * dl], og1 = sg[b][192 + 2 * dl + 1];
      float cn0 = sigm(fg0) * c2.x + sigm(ig0) * tanh_f(gg0);
      float cn1 = sigm(fg1) * c2.y + sigm(ig1) * tanh_f(gg1);
      c2.x = cn0; c2.y = cn1;
      float hx = sigm(og0) * tanh_f(cn0);
      float hy = sigm(og1) * tanh_f(cn1);
      unsigned hp = (unsigned)f2bf(hx) | ((unsigned)f2bf(hy) << 16);
      unsigned* dst = (unsigned*)(h_all + ((size_t)t * BATCH + bg * 16 + b) * HID + q * 64 + 2 * dl);
      __hip_atomic_store(dst, hp, __ATOMIC_RELAXED, __HIP_MEMORY_SCOPE_AGENT);
    }
    if (t < LSTEPS - 1) {
      int r = tid >> 5, k8 = tid & 31;
      *reinterpret_cast<uint4*>(&sx[(t + 1) & 1][(r * 32 + (k8 ^ (r & 7))) * 8]) = xpref;
      if (t < LSTEPS - 2)
        xpref = *reinterpret_cast<const uint4*>(
            &Xbf[(size_t)((t + 2) * BATCH + bg * 16 + r) * HID + k8 * 8]);
    }
    __syncthreads();  // h stores drained, sg consumed, sx[t+1] staged
    if (t < LSTEPS - 1) {
      if (tid == 0)
        __hip_atomic_store(&flags[blockIdx.x * 16], (unsigned)(t + 1), __ATOMIC_RELEASE,
                           __HIP_MEMORY_SCOPE_AGENT);
      // overlap: accx for t+1 (no partner dependency)
      accx[0] = f32x4{};
      accx[1] = f32x4{};
      const u16* sxc = sx[(t + 1) & 1];
#pragma unroll
      for (int kk = 0; kk < 8; ++kk) {
        int k8 = kk * 4 + lk;
        bf16x8 ax = *reinterpret_cast<const bf16x8*>(&sxc[(lr * 32 + (k8 ^ (lr & 7))) * 8]);
        accx[0] = __builtin_amdgcn_mfma_f32_16x16x32_bf16(ax, wih[0][kk], accx[0], 0, 0, 0);
        accx[1] = __builtin_amdgcn_mfma_f32_16x16x32_bf16(ax, wih[1][kk], accx[1], 0, 0, 0);
      }
      if (tid < 3) {
        int pq = (q + 1 + tid) & 3;
        const unsigned* f = &flags[(pq * 8 + bg) * 16];
        int it = 0;
        unsigned v;
        do {
          v = __hip_atomic_load(f, __ATOMIC_ACQUIRE, __HIP_MEMORY_SCOPE_AGENT);
        } while (v <= (unsigned)t && ++it < (1 << 22));
      }
      __syncthreads();
      int r = tid >> 5, k8 = tid & 31;
      const unsigned long long* src =
          (const unsigned long long*)(h_all + ((size_t)t * BATCH + bg * 16 + r) * HID + k8 * 8);
      unsigned long long v0 = __hip_atomic_load(src, __ATOMIC_RELAXED, __HIP_MEMORY_SCOPE_AGENT);
      unsigned long long v1 = __hip_atomic_load(src + 1, __ATOMIC_RELAXED, __HIP_MEMORY_SCOPE_AGENT);
      unsigned long long* d = (unsigned long long*)&sh[(r * 32 + (k8 ^ (r & 7))) * 8];
      d[0] = v0;
      d[1] = v1;
      __syncthreads();
    }
  }
}

extern "C" void kernel_launch(void* const* d_in, const int* in_sizes, int n_in,
                              void* d_out, int out_size, void* d_ws, size_t ws_size,
                              hipStream_t stream) {
  const int* outs = (const int*)d_in[0];
  const float* h0 = (const float*)d_in[1];
  const float* c0 = (const float*)d_in[2];
  const float* embW = (const float*)d_in[4];
  const float* W_ih = (const float*)d_in[5];
  const float* W_hh = (const float*)d_in[6];
  const float* b_ih = (const float*)d_in[7];
  const float* b_hh = (const float*)d_in[8];
  const float* proj_W = (const float*)d_in[9];
  const float* proj_b = (const float*)d_in[10];
  float* out = (float*)d_out;

  char* ws = (char*)d_ws;
  u16* Xbf      = (u16*)(ws + 0);           //  4,194,304 B  [64][128][256] bf16
  u16* WihTp    = (u16*)(ws + 4194304);     //    524,288 B  [32][1024][8]
  u16* WhhTp    = (u16*)(ws + 4718592);     //    524,288 B  [32][1024][8]
  u16* projWbf  = (u16*)(ws + 5242880);     // 16,384,000 B  [32000][256] bf16
  u16* h_all    = (u16*)(ws + 21626880);    //  4,194,304 B  [64][128][256] bf16
  float* bsum   = (float*)(ws + 25821184);  //      4,096 B
  unsigned* flags = (unsigned*)(ws + 25825280);  // 2,048 B

  hipMemsetAsync(flags, 0, 32 * 16 * sizeof(unsigned), stream);
  k_pack<<<dim3(4, 32), 256, 0, stream>>>(W_ih, WihTp, NGATES);
  k_pack<<<dim3(4, 32), 256, 0, stream>>>(W_hh, WhhTp, NGATES);
  k_pack2<<<dim3(4000), 256, 0, stream>>>(proj_W, projWbf);
  k_bsum<<<dim3(4), 256, 0, stream>>>(b_ih, b_hh, bsum);
  k_gather<<<dim3(1024), 256, 0, stream>>>(outs, embW, Xbf);
  k_recur2<<<dim3(32), 512, 0, stream>>>(Xbf, WihTp, WhhTp, bsum, h0, c0, h_all, flags);
  k_gemm2<<<dim3(16000), 256, 0, stream>>>(h_all, projWbf, proj_b, out);
}